// Round 10
// baseline (4517.542 us; speedup 1.0000x reference)
//
#include <hip/hip_runtime.h>

// Problem constants (from reference setup_inputs / NUM_POINTS)
#define BATCH 16
#define NPTS  131072
#define NCH   6
#define KSEL  1024
#define MBLK  16                 // blocks per batch (proven; 32 regressed)
#define TPB   256                // proven geometry (512 kills the harness)
#define CHUNK (NPTS / MBLK)      // 8192 points per block
#define PPT   (CHUNK / TPB)      // 32 points per thread
#define NWAVE (TPB / 64)         // 4
#define ROT   2                  // slot rotation depth (double buffer)

// pub[BATCH][ROT][MBLK] u64 (4 KB), memset 0 before launch.
// Word: [dist_f32_bits:32][~idx:20][tag:12], tag = round k (1..1023).
// All stores/loads RELAXED agent scope. u64 order: max dist first, then
// max ~idx = min global index — jnp.argmax first-occurrence tie-break.
// (dists are squared distances >= 0 -> float-bit ordering == float
// ordering; tag field equal across a round -> never decides the max.)
//
// R22. Model consolidated over R12-R21: round = compute issue ~1400 cyc
// (VALUBusy 22%) + FABRIC SYNC ~2300 (agent-scope atomics serviced at
// die-level coherence point: publish visibility ~900 + poll detect
// ~1.5x900) + barriers/reduce/fetch ~600. Memory tiers all neutral-or-
// worse (R13/14/15/16/20); fan-in changes worse both directions (R21
// MBLK=32: occupancy doubled, dur +38% -> TLP can't hide the inter-block
// hop). Remaining levers are the serial overheads AROUND the hop:
//  (1) PIPELINED POLL: do-while samples once per load latency (~900cyc);
//      4-deep rolling loads (check oldest = vmcnt(3)) cut sampling period
//      to the loop body (~50cyc). Detect ~= visibility + L + 25 instead
//      of + 1.5L. Saves ~400 cyc/round.
//  (2) ALL-WAVES POLL, NO [B], NO s_key: each wave polls the 16 slots
//      itself (lanes<16), 16-lane shfl_xor u64 butterfly + lane-0 bcast.
//      Removes [B], the s_key LDS round-trip and the 16-key serial
//      reduce. Safety: only cross-wave LDS left is s_wkey; a wave reaches
//      its k+1 s_wkey write only after observing own block's round-k
//      publish, which tid0 issues strictly after reading s_wkey (data+
//      control dependency — same hw-ordering the tag protocol itself
//      rests on). ROT=2 without [B]: a k+2 publish requires poll(k+1)
//      done -> all blocks published k+1 -> each block's [A](k+1) -> all
//      its waves finished poll(k). Readers of parity-k slots all done. ✓
//  (3) PACKED-KEY WAVE REDUCE: wave leaders store ready u64 keys to
//      s_wkey[4]; tid0 = 3 u64 max + store (comparator identical).
// R19's failure is attributed to the 64-bit pointer "+v" pin (single-reg
// constraint clobbering the high half), NOT the protocol idea — but the
// publish here stays BLOCK-level (16 slots, R12 layout) regardless.
// R5/R11: multi-word pub records banned; single-key publish only.

extern "C" __global__ __launch_bounds__(TPB)
void fps_kernel(const float* __restrict__ pts, float* __restrict__ out,
                unsigned long long* __restrict__ pub)
{
#pragma clang fp contract(off)
    __shared__ unsigned long long s_wkey[NWAVE];

    const int b    = blockIdx.x % BATCH;     // batch-per-XCD swizzle
    const int m    = blockIdx.x / BATCH;
    const int tid  = threadIdx.x;
    const int wv   = tid >> 6;               // wave id 0..3
    const int lane = tid & 63;
    const int base = m * CHUNK;
    const float* __restrict__ pb = pts + (size_t)b * NPTS * NCH;

    // Staging arrays: the compiler remats these loads into the k-loop and
    // streams coords from XCD-local L2 each round with deep vmcnt
    // batching — measured faster than LDS / SoA / forced-register
    // residency (R13-R16, R20). dmin stays a loop-carried accumulator.
    float xr[PPT], yr[PPT], zr[PPT], dmin[PPT];
#pragma unroll
    for (int i = 0; i < PPT; ++i) {
        const float* p = pb + (size_t)(base + tid + i * TPB) * NCH;
        xr[i]   = p[0];
        yr[i]   = p[1];
        zr[i]   = p[2];
        dmin[i] = __builtin_inff();
    }

    // Selected index 0 -> output row 0.
    if (m == 0 && tid < NCH) out[(size_t)b * KSEL * NCH + tid] = pb[tid];

    // p for round 1 is point 0 (uniform scalar loads of read-only data).
    float px = pb[0], py = pb[1], pz = pb[2];

    for (int k = 1; k < KSEL; ++k) {
        // ---- dist update + thread-local argmax (first-index tie-break) ----
        float bd = -1.0f;
        int   bj = 0;
#pragma unroll
        for (int i = 0; i < PPT; ++i) {
            // Bit-exact replication of the reference's f32 op sequence:
            // each op individually rounded (RN), no FMA / no reassociation.
            float dx = __fsub_rn(xr[i], px);
            float dy = __fsub_rn(yr[i], py);
            float dz = __fsub_rn(zr[i], pz);
            float d  = __fadd_rn(__fadd_rn(__fmul_rn(dx, dx),
                                           __fmul_rn(dy, dy)),
                                 __fmul_rn(dz, dz));
            float dm = dmin[i];
            dm = (d < dm) ? d : dm;
            dmin[i] = dm;
            // j = tid + i*TPB ascends with i: strict '>' keeps first index.
            if (dm > bd) { bd = dm; bj = tid + i * TPB; }
        }

        // ---- wave(64) argmax reduce, smaller index wins ties ----
        for (int off = 32; off > 0; off >>= 1) {
            float od = __shfl_down(bd, off);
            int   oj = __shfl_down(bj, off);
            if (od > bd || (od == bd && oj < bj)) { bd = od; bj = oj; }
        }

        // ---- wave leaders store PACKED keys ----
        if (lane == 0) {
            const unsigned g   = (unsigned)(base + bj);
            const unsigned inv = 0xFFFFFu ^ g;             // 20-bit ~idx
            s_wkey[wv] =
                ((unsigned long long)__float_as_uint(bd) << 32)
                | ((unsigned long long)inv << 12)
                | (unsigned long long)(unsigned)k;         // 12-bit tag
        }
        __syncthreads();                                   // [A]

        unsigned long long* slot =
            pub + ((size_t)b * ROT + (size_t)(k & (ROT - 1))) * MBLK;

        // ---- publish this block's key: 3 u64 max + store (tid 0) ----
        if (tid == 0) {
            unsigned long long kk = s_wkey[0];
#pragma unroll
            for (int w = 1; w < NWAVE; ++w) {
                if (s_wkey[w] > kk) kk = s_wkey[w];
            }
            __hip_atomic_store(&slot[m], kk, __ATOMIC_RELAXED,
                               __HIP_MEMORY_SCOPE_AGENT);
        }

        // ---- every wave polls all 16 slots itself (no [B], no s_key) ----
        // 4-deep rolling pipeline: check the oldest sample (vmcnt(3)) and
        // keep issuing -> sampling period = loop body, not load latency.
        unsigned long long v = 0;
        if (lane < MBLK) {
            unsigned long long a0, a1, a2, a3;
            a0 = __hip_atomic_load(&slot[lane], __ATOMIC_RELAXED,
                                   __HIP_MEMORY_SCOPE_AGENT);
            a1 = __hip_atomic_load(&slot[lane], __ATOMIC_RELAXED,
                                   __HIP_MEMORY_SCOPE_AGENT);
            a2 = __hip_atomic_load(&slot[lane], __ATOMIC_RELAXED,
                                   __HIP_MEMORY_SCOPE_AGENT);
            a3 = __hip_atomic_load(&slot[lane], __ATOMIC_RELAXED,
                                   __HIP_MEMORY_SCOPE_AGENT);
            for (;;) {
                if ((unsigned)(a0 & 0xFFFull) == (unsigned)k) { v = a0; break; }
                a0 = a1; a1 = a2; a2 = a3;
                a3 = __hip_atomic_load(&slot[lane], __ATOMIC_RELAXED,
                                       __HIP_MEMORY_SCOPE_AGENT);
            }
        }
        // 16-lane xor butterfly max (lanes 0-15 closed under xor 8/4/2/1;
        // lanes 16-63 carry v=0, exchange only among themselves).
#pragma unroll
        for (int off = 8; off > 0; off >>= 1) {
            unsigned long long o = __shfl_xor(v, off);
            if (o > v) v = o;
        }
        const unsigned long long mx = __shfl(v, 0);  // broadcast to 64 lanes

        const unsigned g = 0xFFFFFu ^ (unsigned)((mx >> 12) & 0xFFFFFull);
        const float* pp = pb + (size_t)g * NCH;  // same addr all lanes: 1 txn
        px = pp[0]; py = pp[1]; pz = pp[2];

        // Round-robin writer block emits output row k.
        if ((k & (MBLK - 1)) == m && tid == 0) {
            float* o = out + ((size_t)b * KSEL + k) * NCH;
#pragma unroll
            for (int c = 0; c < NCH; ++c) o[c] = pp[c];
        }
    }
}

extern "C" void kernel_launch(void* const* d_in, const int* in_sizes, int n_in,
                              void* d_out, int out_size, void* d_ws, size_t ws_size,
                              hipStream_t stream) {
    const float* pts = (const float*)d_in[0];
    float* out = (float*)d_out;
    unsigned long long* pub = (unsigned long long*)d_ws;

    // pub[BATCH][ROT][MBLK] u64 = 4 KB; zero -> all tags 0 (never match).
    hipMemsetAsync(d_ws, 0,
                   (size_t)BATCH * ROT * MBLK * sizeof(unsigned long long),
                   stream);

    void* args[] = { (void*)&pts, (void*)&out, (void*)&pub };
    hipLaunchCooperativeKernel((const void*)fps_kernel,
                               dim3(BATCH * MBLK), dim3(TPB),
                               args, 0, stream);
}